// Round 1
// baseline (553.093 us; speedup 1.0000x reference)
//
#include <hip/hip_runtime.h>

// NonLocalAttention: channel attention restructured around Gram matrix.
//   G = x x^T (per batch, bf16x3 split precision, fp32 atomic accumulate)
//   logits = Aq G Ak^T + (Aq r) bk^T + bq (Ak r)^T + S*bq bk^T,  Aq = Dq Wq etc.
//   attn = softmax(logits, dim=-1)  (fp32)
//   M = attn Dv Wv (bf16), c = attn bv
//   out = M x + c 1^T + x   (bf16 MFMA, fp32 residual)

typedef __bf16 bf16x8 __attribute__((ext_vector_type(8)));
typedef float f32x4 __attribute__((ext_vector_type(4)));
typedef unsigned short us8 __attribute__((ext_vector_type(8)));

#define EPS 1e-5f

__device__ __forceinline__ unsigned short f2bf(float f) {
  unsigned int u = __float_as_uint(f);
  u += 0x7fffu + ((u >> 16) & 1u);   // round-to-nearest-even
  return (unsigned short)(u >> 16);
}
__device__ __forceinline__ float bf2f(unsigned short h) {
  return __uint_as_float(((unsigned int)h) << 16);
}
__device__ __forceinline__ bf16x8 ld_frag(const unsigned short* p) {
  union { us8 u; bf16x8 b; } x;
  x.u = *(const us8*)p;
  return x.b;
}

// ---------------------------------------------------------------- kZero ----
// G (8*256*256 f32) and r (8*256 f32) are contiguous in ws: 526336 floats.
__global__ void kZero(float* __restrict__ p) {
  p[blockIdx.x * 256 + threadIdx.x] = 0.0f;
}

// ---------------------------------------------------------------- kGram ----
// grid (32 ksplits, 8 batches), 512 threads (8 waves).
// Each WG: full 256x256 partial G over a 512-wide S chunk, bf16 hi/lo split,
// 3-pass MFMA (hh, hl, lh), fp32 atomicAdd into G. Also partial row sums -> r.
#define LDB 72   // padded LDS row stride (bf16 elements); 144B, 16B-aligned
__global__ __launch_bounds__(512, 2) void kGram(const float* __restrict__ x,
                                                float* __restrict__ G,
                                                float* __restrict__ r) {
  __shared__ __align__(16) unsigned short lh[256 * LDB];
  __shared__ __align__(16) unsigned short ll[256 * LDB];
  const int n = blockIdx.y;
  const int k0 = blockIdx.x * 512;
  const int tid = threadIdx.x;
  const float* xn = x + (size_t)n * 4194304;   // 256*16384

  f32x4 acc[2][16];
  const f32x4 z4 = {0.f, 0.f, 0.f, 0.f};
#pragma unroll
  for (int i = 0; i < 2; ++i)
#pragma unroll
    for (int j = 0; j < 16; ++j) acc[i][j] = z4;
  float rs[4] = {0.f, 0.f, 0.f, 0.f};

  const int lane = tid & 63, w = tid >> 6;
  const int m = lane & 15, q = lane >> 4;

  for (int kt = 0; kt < 8; ++kt) {
    const int kb = k0 + kt * 64;
    __syncthreads();
    // stage: 256 rows x 64 k, hi+lo, from fp32 x
#pragma unroll
    for (int u = 0; u < 4; ++u) {
      const int idx = tid + u * 512;
      const int row = idx >> 3, g = idx & 7;
      const float* p = xn + (size_t)row * 16384 + kb + g * 8;
      const float4 v0 = *(const float4*)p;
      const float4 v1 = *(const float4*)(p + 4);
      float fv[8] = {v0.x, v0.y, v0.z, v0.w, v1.x, v1.y, v1.z, v1.w};
      union { unsigned short s[8]; uint4 v; } H, L;
#pragma unroll
      for (int e = 0; e < 8; ++e) {
        const unsigned short h = f2bf(fv[e]);
        H.s[e] = h;
        L.s[e] = f2bf(fv[e] - bf2f(h));
        rs[u] += fv[e];
      }
      *(uint4*)&lh[row * LDB + g * 8] = H.v;
      *(uint4*)&ll[row * LDB + g * 8] = L.v;
    }
    __syncthreads();
#pragma unroll
    for (int kk = 0; kk < 64; kk += 32) {
      bf16x8 Ah[2], Al[2];
#pragma unroll
      for (int i = 0; i < 2; ++i) {
        const int off = (w * 32 + i * 16 + m) * LDB + kk + q * 8;
        Ah[i] = ld_frag(&lh[off]);
        Al[i] = ld_frag(&ll[off]);
      }
#pragma unroll
      for (int j = 0; j < 16; ++j) {
        const int off = (j * 16 + m) * LDB + kk + q * 8;
        const bf16x8 Bh = ld_frag(&lh[off]);
        const bf16x8 Bl = ld_frag(&ll[off]);
#pragma unroll
        for (int i = 0; i < 2; ++i) {
          acc[i][j] = __builtin_amdgcn_mfma_f32_16x16x32_bf16(Ah[i], Bh, acc[i][j], 0, 0, 0);
          acc[i][j] = __builtin_amdgcn_mfma_f32_16x16x32_bf16(Ah[i], Bl, acc[i][j], 0, 0, 0);
          acc[i][j] = __builtin_amdgcn_mfma_f32_16x16x32_bf16(Al[i], Bh, acc[i][j], 0, 0, 0);
        }
      }
    }
  }
  // partial row sums
#pragma unroll
  for (int u = 0; u < 4; ++u) {
    const int row = (tid + u * 512) >> 3;
    atomicAdd(&r[n * 256 + row], rs[u]);
  }
  // C/D layout: col = lane&15, row = (lane>>4)*4 + reg
  float* Gn = G + (size_t)n * 65536;
#pragma unroll
  for (int i = 0; i < 2; ++i)
#pragma unroll
    for (int j = 0; j < 16; ++j)
#pragma unroll
      for (int e = 0; e < 4; ++e) {
        const int grow = w * 32 + i * 16 + q * 4 + e;
        const int gcol = j * 16 + m;
        atomicAdd(&Gn[grow * 256 + gcol], acc[i][j][e]);
      }
}

// ---------------------------------------------------------------- kAttn ----
// grid (16 row-blocks of 16, 8 batches), 256 threads.
// logits -> softmax -> M (bf16) + cvec, all small (256^3 per batch).
__global__ __launch_bounds__(256) void kAttn(
    const float* __restrict__ G, const float* __restrict__ r,
    const float* __restrict__ Wq, const float* __restrict__ qga, const float* __restrict__ qbe,
    const float* __restrict__ qme, const float* __restrict__ qva,
    const float* __restrict__ Wk, const float* __restrict__ kga, const float* __restrict__ kbe,
    const float* __restrict__ kme, const float* __restrict__ kva,
    const float* __restrict__ Wv, const float* __restrict__ vga, const float* __restrict__ vbe,
    const float* __restrict__ vme, const float* __restrict__ vva,
    unsigned short* __restrict__ M, float* __restrict__ cvec) {
  __shared__ float a_lds[16 * 256];   // Aq rows -> later reused for logits/probs
  __shared__ float t_lds[16 * 256];   // T = Aq G
  __shared__ float r_lds[256];
  __shared__ float iv_lds[256], bv_lds[256];
  __shared__ float rq_lds[16], bq_lds[16], rsum_lds[16];

  const int n = blockIdx.y, r0 = blockIdx.x * 16;
  const int t = threadIdx.x;
  const float* Gn = G + (size_t)n * 65536;

  // phase 0: stage
  r_lds[t] = r[n * 256 + t];
  {
    const float iv = vga[t] * rsqrtf(vva[t] + EPS);
    iv_lds[t] = iv;
    bv_lds[t] = vbe[t] - vme[t] * iv;
  }
#pragma unroll
  for (int u = 0; u < 16; ++u) {
    const int idx = t + u * 256;
    const int i = idx >> 8, j = idx & 255;
    const int c = r0 + i;
    const float iv = qga[c] * rsqrtf(qva[c] + EPS);
    a_lds[idx] = iv * Wq[c * 256 + j];
  }
  if (t < 16) {
    const int c = r0 + t;
    const float iv = qga[c] * rsqrtf(qva[c] + EPS);
    bq_lds[t] = qbe[c] - qme[c] * iv;
  }
  __syncthreads();

  // rqv = Aq_rows . r
  if (t < 16) {
    float s = 0.f;
    for (int k2 = 0; k2 < 256; ++k2) s += a_lds[t * 256 + k2] * r_lds[k2];
    rq_lds[t] = s;
  }
  // phase 1: T = Aq G  (thread t = column j)
  float treg[16];
#pragma unroll
  for (int i = 0; i < 16; ++i) treg[i] = 0.f;
  for (int k2 = 0; k2 < 256; ++k2) {
    const float g = Gn[k2 * 256 + t];
#pragma unroll
    for (int i = 0; i < 16; ++i) treg[i] += a_lds[i * 256 + k2] * g;
  }
#pragma unroll
  for (int i = 0; i < 16; ++i) t_lds[i * 256 + t] = treg[i];
  __syncthreads();

  // phase 2: logits = T Ak^T + bias  (thread t = column d)
  float lreg[16];
#pragma unroll
  for (int i = 0; i < 16; ++i) lreg[i] = 0.f;
  const float ivk = kga[t] * rsqrtf(kva[t] + EPS);
  const float bkd = kbe[t] - kme[t] * ivk;
  float rkd = 0.f;
  const float* wkrow = Wk + t * 256;
  for (int j = 0; j < 256; j += 4) {
    const float4 w4 = *(const float4*)&wkrow[j];
    const float b0 = ivk * w4.x, b1 = ivk * w4.y, b2 = ivk * w4.z, b3 = ivk * w4.w;
    rkd += b0 * r_lds[j] + b1 * r_lds[j + 1] + b2 * r_lds[j + 2] + b3 * r_lds[j + 3];
#pragma unroll
    for (int i = 0; i < 16; ++i) {
      lreg[i] += t_lds[i * 256 + j] * b0 + t_lds[i * 256 + j + 1] * b1 +
                 t_lds[i * 256 + j + 2] * b2 + t_lds[i * 256 + j + 3] * b3;
    }
  }
  __syncthreads();
#pragma unroll
  for (int i = 0; i < 16; ++i)
    a_lds[i * 256 + t] = lreg[i] + rq_lds[i] * bkd + bq_lds[i] * rkd + 16384.0f * bq_lds[i] * bkd;
  __syncthreads();

  // phase 3: softmax per row (16 lanes per row)
  {
    const int i = t >> 4, g = t & 15;
    float* row = a_lds + i * 256;
    float mx = -1e30f;
#pragma unroll
    for (int u = 0; u < 16; ++u) mx = fmaxf(mx, row[g + u * 16]);
    mx = fmaxf(mx, __shfl_xor(mx, 1));
    mx = fmaxf(mx, __shfl_xor(mx, 2));
    mx = fmaxf(mx, __shfl_xor(mx, 4));
    mx = fmaxf(mx, __shfl_xor(mx, 8));
    float sm = 0.f;
#pragma unroll
    for (int u = 0; u < 16; ++u) {
      const int d = g + u * 16;
      const float p = __expf(row[d] - mx);
      row[d] = p;
      sm += p;
    }
    sm += __shfl_xor(sm, 1);
    sm += __shfl_xor(sm, 2);
    sm += __shfl_xor(sm, 4);
    sm += __shfl_xor(sm, 8);
    if (g == 0) rsum_lds[i] = sm;
  }
  __syncthreads();

  // phase 4: M = attn Dv Wv (bf16), cvec = attn bv  (thread t = column l)
  float mreg[16];
#pragma unroll
  for (int i = 0; i < 16; ++i) mreg[i] = 0.f;
  for (int d = 0; d < 256; ++d) {
    const float wv = iv_lds[d] * Wv[d * 256 + t];
#pragma unroll
    for (int i = 0; i < 16; ++i) mreg[i] += a_lds[i * 256 + d] * wv;
  }
#pragma unroll
  for (int i = 0; i < 16; ++i) {
    const float inv = 1.0f / rsum_lds[i];
    M[((size_t)n * 256 + r0 + i) * 256 + t] = f2bf(mreg[i] * inv);
  }
  if (t < 16) {
    float cv = 0.f;
    for (int d = 0; d < 256; ++d) cv += a_lds[t * 256 + d] * bv_lds[d];
    cvec[n * 256 + r0 + t] = cv / rsum_lds[t];
  }
}

// ----------------------------------------------------------------- kOut ----
// grid (256 s-chunks of 64, 8 batches), 256 threads (4 waves).
// out[:,s-chunk] = M @ x_bf16 + cvec + x (fp32 residual from LDS copy).
#define LDT 40   // padded LDS row stride for transposed x tile (bf16 elems)
__global__ __launch_bounds__(256, 2) void kOut(const float* __restrict__ x,
                                               const unsigned short* __restrict__ M,
                                               const float* __restrict__ cvec,
                                               float* __restrict__ out) {
  __shared__ __align__(16) unsigned short xt[64 * LDT];  // [s][ch] bf16
  __shared__ __align__(16) float xf[256 * 64];           // [ch][s] fp32 residual
  const int n = blockIdx.y, s0 = blockIdx.x * 64;
  const int tid = threadIdx.x;
  const float* xn = x + (size_t)n * 4194304;
  const unsigned short* Mn = M + (size_t)n * 65536;
  const int lane = tid & 63, w = tid >> 6;
  const int m = lane & 15, q = lane >> 4;

  f32x4 acc[4][4];
  const f32x4 z4 = {0.f, 0.f, 0.f, 0.f};
#pragma unroll
  for (int i = 0; i < 4; ++i)
#pragma unroll
    for (int ct = 0; ct < 4; ++ct) acc[i][ct] = z4;

  for (int kt = 0; kt < 8; ++kt) {
    __syncthreads();
#pragma unroll
    for (int u = 0; u < 2; ++u) {
      const int fidx = tid + u * 256;
      const int ch = fidx >> 4, f = fidx & 15;
      const float4 v = *(const float4*)(xn + (size_t)(kt * 32 + ch) * 16384 + s0 + f * 4);
      *(float4*)&xf[(kt * 32 + ch) * 64 + f * 4] = v;
      xt[(f * 4 + 0) * LDT + ch] = f2bf(v.x);
      xt[(f * 4 + 1) * LDT + ch] = f2bf(v.y);
      xt[(f * 4 + 2) * LDT + ch] = f2bf(v.z);
      xt[(f * 4 + 3) * LDT + ch] = f2bf(v.w);
    }
    __syncthreads();
    bf16x8 A[4], B[4];
#pragma unroll
    for (int i = 0; i < 4; ++i)
      A[i] = ld_frag(&Mn[((w * 4 + i) * 16 + m) * 256 + kt * 32 + q * 8]);
#pragma unroll
    for (int ct = 0; ct < 4; ++ct)
      B[ct] = ld_frag(&xt[(ct * 16 + m) * LDT + q * 8]);
#pragma unroll
    for (int i = 0; i < 4; ++i)
#pragma unroll
      for (int ct = 0; ct < 4; ++ct)
        acc[i][ct] = __builtin_amdgcn_mfma_f32_16x16x32_bf16(A[i], B[ct], acc[i][ct], 0, 0, 0);
  }
  // epilogue: c = w*64 + i*16 + q*4 + e ; s = ct*16 + m
#pragma unroll
  for (int i = 0; i < 4; ++i) {
    const int cb = w * 64 + i * 16 + q * 4;
#pragma unroll
    for (int e = 0; e < 4; ++e) {
      const int c = cb + e;
      const float cv = cvec[n * 256 + c];
      float* orow = out + ((size_t)n * 256 + c) * 16384 + s0;
#pragma unroll
      for (int ct = 0; ct < 4; ++ct) {
        const int s = ct * 16 + m;
        orow[s] = acc[i][ct][e] + cv + xf[c * 64 + s];
      }
    }
  }
}

// --------------------------------------------------------------- launch ----
extern "C" void kernel_launch(void* const* d_in, const int* in_sizes, int n_in,
                              void* d_out, int out_size, void* d_ws, size_t ws_size,
                              hipStream_t stream) {
  const float* x   = (const float*)d_in[0];
  const float* Wk  = (const float*)d_in[1];
  const float* kga = (const float*)d_in[2];
  const float* kbe = (const float*)d_in[3];
  const float* kme = (const float*)d_in[4];
  const float* kva = (const float*)d_in[5];
  const float* Wq  = (const float*)d_in[6];
  const float* qga = (const float*)d_in[7];
  const float* qbe = (const float*)d_in[8];
  const float* qme = (const float*)d_in[9];
  const float* qva = (const float*)d_in[10];
  const float* Wv  = (const float*)d_in[11];
  const float* vga = (const float*)d_in[12];
  const float* vbe = (const float*)d_in[13];
  const float* vme = (const float*)d_in[14];
  const float* vva = (const float*)d_in[15];

  char* ws = (char*)d_ws;
  float* G            = (float*)(ws);                 // 8*256*256*4 = 2097152 B
  float* rsum         = (float*)(ws + 2097152);       // 8*256*4    = 8192 B
  unsigned short* Mm  = (unsigned short*)(ws + 2105344);  // 8*256*256*2 = 1048576 B
  float* cv           = (float*)(ws + 3153920);       // 8*256*4    = 8192 B
  float* out          = (float*)d_out;

  kZero<<<2056, 256, 0, stream>>>(G);   // zeros G and rsum (contiguous 526336 floats)
  kGram<<<dim3(32, 8), 512, 0, stream>>>(x, G, rsum);
  kAttn<<<dim3(16, 8), 256, 0, stream>>>(G, rsum,
                                         Wq, qga, qbe, qme, qva,
                                         Wk, kga, kbe, kme, kva,
                                         Wv, vga, vbe, vme, vva,
                                         Mm, cv);
  kOut<<<dim3(256, 8), 256, 0, stream>>>(x, Mm, cv, out);
}

// Round 2
// 417.183 us; speedup vs baseline: 1.3258x; 1.3258x over previous
//
#include <hip/hip_runtime.h>

// NonLocalAttention: channel attention restructured around Gram matrix.
//   G = x x^T (per batch, bf16x3 split precision, split-k partials + tree reduce)
//   logits = Aq G Ak^T + (Aq r) bk^T + bq (Ak r)^T + S*bq bk^T,  Aq = Dq Wq etc.
//   attn = softmax(logits, dim=-1)  (fp32)
//   M = attn Dv Wv (bf16), c = attn bv
//   out = M x + c 1^T + x   (bf16 MFMA, fp32 residual)
//
// R1 change: kGram atomicAdd (16.8M contended fp32 RMWs -> 78 MB HBM write-through,
// 239 us at 8.5% MfmaUtil) replaced by per-split partial stores + kReduce.
// r row-sums via __shfl_xor in-wave reduction, no atomics. kZero dropped.

typedef __bf16 bf16x8 __attribute__((ext_vector_type(8)));
typedef float f32x4 __attribute__((ext_vector_type(4)));
typedef unsigned short us8 __attribute__((ext_vector_type(8)));

#define EPS 1e-5f

__device__ __forceinline__ unsigned short f2bf(float f) {
  unsigned int u = __float_as_uint(f);
  u += 0x7fffu + ((u >> 16) & 1u);   // round-to-nearest-even
  return (unsigned short)(u >> 16);
}
__device__ __forceinline__ float bf2f(unsigned short h) {
  return __uint_as_float(((unsigned int)h) << 16);
}
__device__ __forceinline__ bf16x8 ld_frag(const unsigned short* p) {
  union { us8 u; bf16x8 b; } x;
  x.u = *(const us8*)p;
  return x.b;
}

// ---------------------------------------------------------------- kGram ----
// grid (splits, 8 batches), 512 threads (8 waves).
// Each WG: full 256x256 partial G over a `chunk`-wide S range, bf16 hi/lo split,
// 3-pass MFMA (hh, hl, lh), plain stores into its private Gp slot.
#define LDB 72   // padded LDS row stride (bf16 elements); 144B, 16B-aligned
__global__ __launch_bounds__(512, 2) void kGram(const float* __restrict__ x,
                                                float* __restrict__ Gp,
                                                float* __restrict__ rp,
                                                int chunk) {
  __shared__ __align__(16) unsigned short lh[256 * LDB];
  __shared__ __align__(16) unsigned short ll[256 * LDB];
  const int n = blockIdx.y;
  const int k0 = blockIdx.x * chunk;
  const int nkt = chunk >> 6;
  const int tid = threadIdx.x;
  const float* xn = x + (size_t)n * 4194304;   // 256*16384

  f32x4 acc[2][16];
  const f32x4 z4 = {0.f, 0.f, 0.f, 0.f};
#pragma unroll
  for (int i = 0; i < 2; ++i)
#pragma unroll
    for (int j = 0; j < 16; ++j) acc[i][j] = z4;
  float rs[4] = {0.f, 0.f, 0.f, 0.f};

  const int lane = tid & 63, w = tid >> 6;
  const int m = lane & 15, q = lane >> 4;

  for (int kt = 0; kt < nkt; ++kt) {
    const int kb = k0 + kt * 64;
    __syncthreads();
    // stage: 256 rows x 64 k, hi+lo, from fp32 x
#pragma unroll
    for (int u = 0; u < 4; ++u) {
      const int idx = tid + u * 512;
      const int row = idx >> 3, g = idx & 7;
      const float* p = xn + (size_t)row * 16384 + kb + g * 8;
      const float4 v0 = *(const float4*)p;
      const float4 v1 = *(const float4*)(p + 4);
      float fv[8] = {v0.x, v0.y, v0.z, v0.w, v1.x, v1.y, v1.z, v1.w};
      union { unsigned short s[8]; uint4 v; } H, L;
#pragma unroll
      for (int e = 0; e < 8; ++e) {
        const unsigned short h = f2bf(fv[e]);
        H.s[e] = h;
        L.s[e] = f2bf(fv[e] - bf2f(h));
        rs[u] += fv[e];
      }
      *(uint4*)&lh[row * LDB + g * 8] = H.v;
      *(uint4*)&ll[row * LDB + g * 8] = L.v;
    }
    __syncthreads();
#pragma unroll
    for (int kk = 0; kk < 64; kk += 32) {
      bf16x8 Ah[2], Al[2];
#pragma unroll
      for (int i = 0; i < 2; ++i) {
        const int off = (w * 32 + i * 16 + m) * LDB + kk + q * 8;
        Ah[i] = ld_frag(&lh[off]);
        Al[i] = ld_frag(&ll[off]);
      }
#pragma unroll
      for (int j = 0; j < 16; ++j) {
        const int off = (j * 16 + m) * LDB + kk + q * 8;
        const bf16x8 Bh = ld_frag(&lh[off]);
        const bf16x8 Bl = ld_frag(&ll[off]);
#pragma unroll
        for (int i = 0; i < 2; ++i) {
          acc[i][j] = __builtin_amdgcn_mfma_f32_16x16x32_bf16(Ah[i], Bh, acc[i][j], 0, 0, 0);
          acc[i][j] = __builtin_amdgcn_mfma_f32_16x16x32_bf16(Ah[i], Bl, acc[i][j], 0, 0, 0);
          acc[i][j] = __builtin_amdgcn_mfma_f32_16x16x32_bf16(Al[i], Bh, acc[i][j], 0, 0, 0);
        }
      }
    }
  }
  const size_t slot = (size_t)n * gridDim.x + blockIdx.x;
  // partial row sums: rows are owned by aligned groups of 8 lanes (bits 0..2)
#pragma unroll
  for (int u = 0; u < 4; ++u) {
    float v = rs[u];
    v += __shfl_xor(v, 1);
    v += __shfl_xor(v, 2);
    v += __shfl_xor(v, 4);
    if ((lane & 7) == 0) rp[slot * 256 + ((tid + u * 512) >> 3)] = v;
  }
  // C/D layout: col = lane&15, row = (lane>>4)*4 + reg
  float* Gpn = Gp + slot * 65536;
#pragma unroll
  for (int i = 0; i < 2; ++i)
#pragma unroll
    for (int j = 0; j < 16; ++j)
#pragma unroll
      for (int e = 0; e < 4; ++e) {
        const int grow = w * 32 + i * 16 + q * 4 + e;
        const int gcol = j * 16 + m;
        Gpn[grow * 256 + gcol] = acc[i][j][e];
      }
}

// -------------------------------------------------------------- kReduce ----
// grid 2048 x 256: one thread per G element, sums `splits` partials.
__global__ void kReduce(const float* __restrict__ Gp, float* __restrict__ G,
                        int splits) {
  const int e = blockIdx.x * 256 + threadIdx.x;   // 0 .. 524287
  const int n = e >> 16, el = e & 65535;
  const float* p = Gp + (size_t)n * splits * 65536 + el;
  float s = 0.f;
  for (int i = 0; i < splits; ++i) s += p[(size_t)i * 65536];
  G[e] = s;
}

// ---------------------------------------------------------------- kAttn ----
// grid (16 row-blocks of 16, 8 batches), 256 threads.
// logits -> softmax -> M (bf16) + cvec, all small (256^3 per batch).
__global__ __launch_bounds__(256) void kAttn(
    const float* __restrict__ G, const float* __restrict__ rp, int splits,
    const float* __restrict__ Wq, const float* __restrict__ qga, const float* __restrict__ qbe,
    const float* __restrict__ qme, const float* __restrict__ qva,
    const float* __restrict__ Wk, const float* __restrict__ kga, const float* __restrict__ kbe,
    const float* __restrict__ kme, const float* __restrict__ kva,
    const float* __restrict__ Wv, const float* __restrict__ vga, const float* __restrict__ vbe,
    const float* __restrict__ vme, const float* __restrict__ vva,
    unsigned short* __restrict__ M, float* __restrict__ cvec) {
  __shared__ float a_lds[16 * 256];   // Aq rows -> later reused for logits/probs
  __shared__ float t_lds[16 * 256];   // T = Aq G
  __shared__ float r_lds[256];
  __shared__ float iv_lds[256], bv_lds[256];
  __shared__ float rq_lds[16], bq_lds[16], rsum_lds[16];

  const int n = blockIdx.y, r0 = blockIdx.x * 16;
  const int t = threadIdx.x;
  const float* Gn = G + (size_t)n * 65536;

  // phase 0: stage (r = sum of per-split partial row sums)
  {
    float s = 0.f;
    const float* p = rp + (size_t)n * splits * 256 + t;
    for (int ss = 0; ss < splits; ++ss) s += p[ss * 256];
    r_lds[t] = s;
  }
  {
    const float iv = vga[t] * rsqrtf(vva[t] + EPS);
    iv_lds[t] = iv;
    bv_lds[t] = vbe[t] - vme[t] * iv;
  }
#pragma unroll
  for (int u = 0; u < 16; ++u) {
    const int idx = t + u * 256;
    const int i = idx >> 8, j = idx & 255;
    const int c = r0 + i;
    const float iv = qga[c] * rsqrtf(qva[c] + EPS);
    a_lds[idx] = iv * Wq[c * 256 + j];
  }
  if (t < 16) {
    const int c = r0 + t;
    const float iv = qga[c] * rsqrtf(qva[c] + EPS);
    bq_lds[t] = qbe[c] - qme[c] * iv;
  }
  __syncthreads();

  // rqv = Aq_rows . r
  if (t < 16) {
    float s = 0.f;
    for (int k2 = 0; k2 < 256; ++k2) s += a_lds[t * 256 + k2] * r_lds[k2];
    rq_lds[t] = s;
  }
  // phase 1: T = Aq G  (thread t = column j)
  float treg[16];
#pragma unroll
  for (int i = 0; i < 16; ++i) treg[i] = 0.f;
  for (int k2 = 0; k2 < 256; ++k2) {
    const float g = Gn[k2 * 256 + t];
#pragma unroll
    for (int i = 0; i < 16; ++i) treg[i] += a_lds[i * 256 + k2] * g;
  }
#pragma unroll
  for (int i = 0; i < 16; ++i) t_lds[i * 256 + t] = treg[i];
  __syncthreads();

  // phase 2: logits = T Ak^T + bias  (thread t = column d)
  float lreg[16];
#pragma unroll
  for (int i = 0; i < 16; ++i) lreg[i] = 0.f;
  const float ivk = kga[t] * rsqrtf(kva[t] + EPS);
  const float bkd = kbe[t] - kme[t] * ivk;
  float rkd = 0.f;
  const float* wkrow = Wk + t * 256;
  for (int j = 0; j < 256; j += 4) {
    const float4 w4 = *(const float4*)&wkrow[j];
    const float b0 = ivk * w4.x, b1 = ivk * w4.y, b2 = ivk * w4.z, b3 = ivk * w4.w;
    rkd += b0 * r_lds[j] + b1 * r_lds[j + 1] + b2 * r_lds[j + 2] + b3 * r_lds[j + 3];
#pragma unroll
    for (int i = 0; i < 16; ++i) {
      lreg[i] += t_lds[i * 256 + j] * b0 + t_lds[i * 256 + j + 1] * b1 +
                 t_lds[i * 256 + j + 2] * b2 + t_lds[i * 256 + j + 3] * b3;
    }
  }
  __syncthreads();
#pragma unroll
  for (int i = 0; i < 16; ++i)
    a_lds[i * 256 + t] = lreg[i] + rq_lds[i] * bkd + bq_lds[i] * rkd + 16384.0f * bq_lds[i] * bkd;
  __syncthreads();

  // phase 3: softmax per row (16 lanes per row)
  {
    const int i = t >> 4, g = t & 15;
    float* row = a_lds + i * 256;
    float mx = -1e30f;
#pragma unroll
    for (int u = 0; u < 16; ++u) mx = fmaxf(mx, row[g + u * 16]);
    mx = fmaxf(mx, __shfl_xor(mx, 1));
    mx = fmaxf(mx, __shfl_xor(mx, 2));
    mx = fmaxf(mx, __shfl_xor(mx, 4));
    mx = fmaxf(mx, __shfl_xor(mx, 8));
    float sm = 0.f;
#pragma unroll
    for (int u = 0; u < 16; ++u) {
      const int d = g + u * 16;
      const float p = __expf(row[d] - mx);
      row[d] = p;
      sm += p;
    }
    sm += __shfl_xor(sm, 1);
    sm += __shfl_xor(sm, 2);
    sm += __shfl_xor(sm, 4);
    sm += __shfl_xor(sm, 8);
    if (g == 0) rsum_lds[i] = sm;
  }
  __syncthreads();

  // phase 4: M = attn Dv Wv (bf16), cvec = attn bv  (thread t = column l)
  float mreg[16];
#pragma unroll
  for (int i = 0; i < 16; ++i) mreg[i] = 0.f;
  for (int d = 0; d < 256; ++d) {
    const float wv = iv_lds[d] * Wv[d * 256 + t];
#pragma unroll
    for (int i = 0; i < 16; ++i) mreg[i] += a_lds[i * 256 + d] * wv;
  }
#pragma unroll
  for (int i = 0; i < 16; ++i) {
    const float inv = 1.0f / rsum_lds[i];
    M[((size_t)n * 256 + r0 + i) * 256 + t] = f2bf(mreg[i] * inv);
  }
  if (t < 16) {
    float cv = 0.f;
    for (int d = 0; d < 256; ++d) cv += a_lds[t * 256 + d] * bv_lds[d];
    cvec[n * 256 + r0 + t] = cv / rsum_lds[t];
  }
}

// ----------------------------------------------------------------- kOut ----
// grid (256 s-chunks of 64, 8 batches), 256 threads (4 waves).
// out[:,s-chunk] = M @ x_bf16 + cvec + x (fp32 residual from LDS copy).
#define LDT 40   // padded LDS row stride for transposed x tile (bf16 elems)
__global__ __launch_bounds__(256, 2) void kOut(const float* __restrict__ x,
                                               const unsigned short* __restrict__ M,
                                               const float* __restrict__ cvec,
                                               float* __restrict__ out) {
  __shared__ __align__(16) unsigned short xt[64 * LDT];  // [s][ch] bf16
  __shared__ __align__(16) float xf[256 * 64];           // [ch][s] fp32 residual
  const int n = blockIdx.y, s0 = blockIdx.x * 64;
  const int tid = threadIdx.x;
  const float* xn = x + (size_t)n * 4194304;
  const unsigned short* Mn = M + (size_t)n * 65536;
  const int lane = tid & 63, w = tid >> 6;
  const int m = lane & 15, q = lane >> 4;

  f32x4 acc[4][4];
  const f32x4 z4 = {0.f, 0.f, 0.f, 0.f};
#pragma unroll
  for (int i = 0; i < 4; ++i)
#pragma unroll
    for (int ct = 0; ct < 4; ++ct) acc[i][ct] = z4;

  for (int kt = 0; kt < 8; ++kt) {
    __syncthreads();
#pragma unroll
    for (int u = 0; u < 2; ++u) {
      const int fidx = tid + u * 256;
      const int ch = fidx >> 4, f = fidx & 15;
      const float4 v = *(const float4*)(xn + (size_t)(kt * 32 + ch) * 16384 + s0 + f * 4);
      *(float4*)&xf[(kt * 32 + ch) * 64 + f * 4] = v;
      xt[(f * 4 + 0) * LDT + ch] = f2bf(v.x);
      xt[(f * 4 + 1) * LDT + ch] = f2bf(v.y);
      xt[(f * 4 + 2) * LDT + ch] = f2bf(v.z);
      xt[(f * 4 + 3) * LDT + ch] = f2bf(v.w);
    }
    __syncthreads();
    bf16x8 A[4], B[4];
#pragma unroll
    for (int i = 0; i < 4; ++i)
      A[i] = ld_frag(&Mn[((w * 4 + i) * 16 + m) * 256 + kt * 32 + q * 8]);
#pragma unroll
    for (int ct = 0; ct < 4; ++ct)
      B[ct] = ld_frag(&xt[(ct * 16 + m) * LDT + q * 8]);
#pragma unroll
    for (int i = 0; i < 4; ++i)
#pragma unroll
      for (int ct = 0; ct < 4; ++ct)
        acc[i][ct] = __builtin_amdgcn_mfma_f32_16x16x32_bf16(A[i], B[ct], acc[i][ct], 0, 0, 0);
  }
  // epilogue: c = w*64 + i*16 + q*4 + e ; s = ct*16 + m
#pragma unroll
  for (int i = 0; i < 4; ++i) {
    const int cb = w * 64 + i * 16 + q * 4;
#pragma unroll
    for (int e = 0; e < 4; ++e) {
      const int c = cb + e;
      const float cv = cvec[n * 256 + c];
      float* orow = out + ((size_t)n * 256 + c) * 16384 + s0;
#pragma unroll
      for (int ct = 0; ct < 4; ++ct) {
        const int s = ct * 16 + m;
        orow[s] = acc[i][ct][e] + cv + xf[c * 64 + s];
      }
    }
  }
}

// --------------------------------------------------------------- launch ----
extern "C" void kernel_launch(void* const* d_in, const int* in_sizes, int n_in,
                              void* d_out, int out_size, void* d_ws, size_t ws_size,
                              hipStream_t stream) {
  const float* x   = (const float*)d_in[0];
  const float* Wk  = (const float*)d_in[1];
  const float* kga = (const float*)d_in[2];
  const float* kbe = (const float*)d_in[3];
  const float* kme = (const float*)d_in[4];
  const float* kva = (const float*)d_in[5];
  const float* Wq  = (const float*)d_in[6];
  const float* qga = (const float*)d_in[7];
  const float* qbe = (const float*)d_in[8];
  const float* qme = (const float*)d_in[9];
  const float* qva = (const float*)d_in[10];
  const float* Wv  = (const float*)d_in[11];
  const float* vga = (const float*)d_in[12];
  const float* vbe = (const float*)d_in[13];
  const float* vme = (const float*)d_in[14];
  const float* vva = (const float*)d_in[15];

  // ws layout: G (2 MB) | M (1 MB) | cvec (8 KB) | rp (256 KB) | Gp (splits*2 MB)
  char* ws = (char*)d_ws;
  float* G           = (float*)(ws);
  unsigned short* Mm = (unsigned short*)(ws + 2097152);
  float* cv          = (float*)(ws + 3145728);
  float* rp          = (float*)(ws + 3153920);
  float* Gp          = (float*)(ws + 3416064);
  float* out         = (float*)d_out;

  int splits = 32;
  while (splits > 1 &&
         (size_t)3416064 + (size_t)splits * 8 * 65536 * 4 > ws_size)
    splits >>= 1;
  const int chunk = 16384 / splits;

  kGram<<<dim3(splits, 8), 512, 0, stream>>>(x, Gp, rp, chunk);
  kReduce<<<2048, 256, 0, stream>>>(Gp, G, splits);
  kAttn<<<dim3(16, 8), 256, 0, stream>>>(G, rp, splits,
                                         Wq, qga, qbe, qme, qva,
                                         Wk, kga, kbe, kme, kva,
                                         Wv, vga, vbe, vme, vva,
                                         Mm, cv);
  kOut<<<dim3(256, 8), 256, 0, stream>>>(x, Mm, cv, out);
}

// Round 3
// 390.674 us; speedup vs baseline: 1.4157x; 1.0679x over previous
//
#include <hip/hip_runtime.h>

// NonLocalAttention: channel attention restructured around Gram matrix.
//   G = x x^T (per batch, bf16x3 split precision, split-k partials + tree reduce)
//   logits = Aq G Ak^T + (Aq r) bk^T + bq (Ak r)^T + S*bq bk^T,  Aq = Dq Wq etc.
//   attn = softmax(logits, dim=-1)  (fp32)
//   M = attn Dv Wv (bf16), c = attn bv
//   out = M x + c 1^T + x   (bf16 MFMA, fp32 residual)
//
// R2 change: kAttn was LDS-issue/latency bound (88 us, VALUBusy 16%, occ 5.4%:
// ~12K scalar ds_read_b32 broadcasts/thread, 128 WGs). Rewritten: wave-uniform
// Wq operand moved to scalar pipe (s_load via readfirstlane-forced uniform
// addresses), remaining uniform LDS reads vectorized to b128, grid 128->256 WGs
// (8 rows/WG). kReduce float4-ized.

typedef __bf16 bf16x8 __attribute__((ext_vector_type(8)));
typedef float f32x4 __attribute__((ext_vector_type(4)));
typedef unsigned short us8 __attribute__((ext_vector_type(8)));

#define EPS 1e-5f

__device__ __forceinline__ unsigned short f2bf(float f) {
  unsigned int u = __float_as_uint(f);
  u += 0x7fffu + ((u >> 16) & 1u);   // round-to-nearest-even
  return (unsigned short)(u >> 16);
}
__device__ __forceinline__ float bf2f(unsigned short h) {
  return __uint_as_float(((unsigned int)h) << 16);
}
__device__ __forceinline__ bf16x8 ld_frag(const unsigned short* p) {
  union { us8 u; bf16x8 b; } x;
  x.u = *(const us8*)p;
  return x.b;
}

// ---------------------------------------------------------------- kGram ----
// grid (splits, 8 batches), 512 threads (8 waves).
// Each WG: full 256x256 partial G over a `chunk`-wide S range, bf16 hi/lo split,
// 3-pass MFMA (hh, hl, lh), plain stores into its private Gp slot.
#define LDB 72   // padded LDS row stride (bf16 elements); 144B, 16B-aligned
__global__ __launch_bounds__(512, 2) void kGram(const float* __restrict__ x,
                                                float* __restrict__ Gp,
                                                float* __restrict__ rp,
                                                int chunk) {
  __shared__ __align__(16) unsigned short lh[256 * LDB];
  __shared__ __align__(16) unsigned short ll[256 * LDB];
  const int n = blockIdx.y;
  const int k0 = blockIdx.x * chunk;
  const int nkt = chunk >> 6;
  const int tid = threadIdx.x;
  const float* xn = x + (size_t)n * 4194304;   // 256*16384

  f32x4 acc[2][16];
  const f32x4 z4 = {0.f, 0.f, 0.f, 0.f};
#pragma unroll
  for (int i = 0; i < 2; ++i)
#pragma unroll
    for (int j = 0; j < 16; ++j) acc[i][j] = z4;
  float rs[4] = {0.f, 0.f, 0.f, 0.f};

  const int lane = tid & 63, w = tid >> 6;
  const int m = lane & 15, q = lane >> 4;

  for (int kt = 0; kt < nkt; ++kt) {
    const int kb = k0 + kt * 64;
    __syncthreads();
    // stage: 256 rows x 64 k, hi+lo, from fp32 x
#pragma unroll
    for (int u = 0; u < 4; ++u) {
      const int idx = tid + u * 512;
      const int row = idx >> 3, g = idx & 7;
      const float* p = xn + (size_t)row * 16384 + kb + g * 8;
      const float4 v0 = *(const float4*)p;
      const float4 v1 = *(const float4*)(p + 4);
      float fv[8] = {v0.x, v0.y, v0.z, v0.w, v1.x, v1.y, v1.z, v1.w};
      union { unsigned short s[8]; uint4 v; } H, L;
#pragma unroll
      for (int e = 0; e < 8; ++e) {
        const unsigned short h = f2bf(fv[e]);
        H.s[e] = h;
        L.s[e] = f2bf(fv[e] - bf2f(h));
        rs[u] += fv[e];
      }
      *(uint4*)&lh[row * LDB + g * 8] = H.v;
      *(uint4*)&ll[row * LDB + g * 8] = L.v;
    }
    __syncthreads();
#pragma unroll
    for (int kk = 0; kk < 64; kk += 32) {
      bf16x8 Ah[2], Al[2];
#pragma unroll
      for (int i = 0; i < 2; ++i) {
        const int off = (w * 32 + i * 16 + m) * LDB + kk + q * 8;
        Ah[i] = ld_frag(&lh[off]);
        Al[i] = ld_frag(&ll[off]);
      }
#pragma unroll
      for (int j = 0; j < 16; ++j) {
        const int off = (j * 16 + m) * LDB + kk + q * 8;
        const bf16x8 Bh = ld_frag(&lh[off]);
        const bf16x8 Bl = ld_frag(&ll[off]);
#pragma unroll
        for (int i = 0; i < 2; ++i) {
          acc[i][j] = __builtin_amdgcn_mfma_f32_16x16x32_bf16(Ah[i], Bh, acc[i][j], 0, 0, 0);
          acc[i][j] = __builtin_amdgcn_mfma_f32_16x16x32_bf16(Ah[i], Bl, acc[i][j], 0, 0, 0);
          acc[i][j] = __builtin_amdgcn_mfma_f32_16x16x32_bf16(Al[i], Bh, acc[i][j], 0, 0, 0);
        }
      }
    }
  }
  const size_t slot = (size_t)n * gridDim.x + blockIdx.x;
  // partial row sums: rows are owned by aligned groups of 8 lanes (bits 0..2)
#pragma unroll
  for (int u = 0; u < 4; ++u) {
    float v = rs[u];
    v += __shfl_xor(v, 1);
    v += __shfl_xor(v, 2);
    v += __shfl_xor(v, 4);
    if ((lane & 7) == 0) rp[slot * 256 + ((tid + u * 512) >> 3)] = v;
  }
  // C/D layout: col = lane&15, row = (lane>>4)*4 + reg
  float* Gpn = Gp + slot * 65536;
#pragma unroll
  for (int i = 0; i < 2; ++i)
#pragma unroll
    for (int j = 0; j < 16; ++j)
#pragma unroll
      for (int e = 0; e < 4; ++e) {
        const int grow = w * 32 + i * 16 + q * 4 + e;
        const int gcol = j * 16 + m;
        Gpn[grow * 256 + gcol] = acc[i][j][e];
      }
}

// -------------------------------------------------------------- kReduce ----
// grid 512 x 256: one thread per 4 G elements (float4), sums `splits` partials.
__global__ void kReduce(const float* __restrict__ Gp, float* __restrict__ G,
                        int splits) {
  const int e4 = (blockIdx.x * 256 + threadIdx.x) * 4;   // 0 .. 524284
  const int n = e4 >> 16, el = e4 & 65535;
  const float* p = Gp + (size_t)n * splits * 65536 + el;
  float4 s = {0.f, 0.f, 0.f, 0.f};
  for (int i = 0; i < splits; ++i) {
    const float4 v = *(const float4*)(p + (size_t)i * 65536);
    s.x += v.x; s.y += v.y; s.z += v.z; s.w += v.w;
  }
  *(float4*)(G + e4) = s;
}

// ---------------------------------------------------------------- kAttn ----
// grid (32 row-blocks of 8, 8 batches), 256 threads (4 waves).
// P1: T = ivq*(Wq G): Wq rows via scalar pipe (uniform s_load), G via
//     lane-contiguous float4; wave w owns rows {2w, 2w+1}, lane owns 4 cols.
// P2: L = ivk*(T Wk^T) + bias: thread = col d, T rows via uniform b128.
// P3: softmax (32 lanes per row), P pre-scaled by ivv, cvec fused.
// P4: M = (P Wv)/rsum: thread = col l, P via uniform b128, Wv coalesced.
#define TLD 260   // padded fp32 LDS row stride (16B-aligned: 260*4 = 1040)
__global__ __launch_bounds__(256) void kAttn(
    const float* __restrict__ G, const float* __restrict__ rp, int splits,
    const float* __restrict__ Wq, const float* __restrict__ qga, const float* __restrict__ qbe,
    const float* __restrict__ qme, const float* __restrict__ qva,
    const float* __restrict__ Wk, const float* __restrict__ kga, const float* __restrict__ kbe,
    const float* __restrict__ kme, const float* __restrict__ kva,
    const float* __restrict__ Wv, const float* __restrict__ vga, const float* __restrict__ vbe,
    const float* __restrict__ vme, const float* __restrict__ vva,
    unsigned short* __restrict__ M, float* __restrict__ cvec) {
  __shared__ __align__(16) float t_lds[8 * TLD];
  __shared__ __align__(16) float p_lds[8 * TLD];
  __shared__ __align__(16) float r_lds[256];
  __shared__ float ivv_lds[256], bv_lds[256];
  __shared__ float rq_lds[8], bq_lds[8], rsum_lds[8];

  const int n = blockIdx.y, r0 = blockIdx.x * 8;
  const int t = threadIdx.x;
  const int lane = t & 63;
  const int w = __builtin_amdgcn_readfirstlane(t >> 6);  // force SGPR
  const float* Gn = G + (size_t)n * 65536;

  // stage r (sum of split partials), ivv, bv
  {
    float s = 0.f;
    const float* p = rp + (size_t)n * splits * 256 + t;
    for (int ss = 0; ss < splits; ++ss) s += p[ss * 256];
    r_lds[t] = s;
    const float iv = vga[t] * rsqrtf(vva[t] + EPS);
    ivv_lds[t] = iv;
    bv_lds[t] = vbe[t] - vme[t] * iv;
  }
  __syncthreads();

  // ------- P1: wave w owns rows c0 = r0+2w, c1 = c0+1; lane owns cols 4l..4l+3
  const int c0 = r0 + 2 * w, c1 = c0 + 1;
  const float ivq0 = qga[c0] * rsqrtf(qva[c0] + EPS);
  const float ivq1 = qga[c1] * rsqrtf(qva[c1] + EPS);

  // rq_i = ivq_i * (Wq_row_i . r)  (lane-parallel dot + wave reduce)
  {
    const float4 r4 = *(const float4*)(r_lds + lane * 4);
#pragma unroll
    for (int rr = 0; rr < 2; ++rr) {
      const float4 w4 = *(const float4*)(Wq + (size_t)(c0 + rr) * 256 + lane * 4);
      float s = w4.x * r4.x + w4.y * r4.y + w4.z * r4.z + w4.w * r4.w;
      s += __shfl_xor(s, 1);  s += __shfl_xor(s, 2);  s += __shfl_xor(s, 4);
      s += __shfl_xor(s, 8);  s += __shfl_xor(s, 16); s += __shfl_xor(s, 32);
      if (lane == 0) rq_lds[2 * w + rr] = s * (rr ? ivq1 : ivq0);
    }
    if (lane == 0) {
      bq_lds[2 * w + 0] = qbe[c0] - qme[c0] * ivq0;
      bq_lds[2 * w + 1] = qbe[c1] - qme[c1] * ivq1;
    }
  }

  // T rows: treg[2][4] over K=256; Wq via scalar pipe, G via float4
  {
    float4 tr0 = {0.f, 0.f, 0.f, 0.f}, tr1 = {0.f, 0.f, 0.f, 0.f};
    const float* wq0 = Wq + (size_t)c0 * 256;
    const float* wq1 = Wq + (size_t)c1 * 256;
    for (int kb = 0; kb < 256; kb += 4) {
      union { float4 v; float f[4]; } A0, A1;
      A0.v = *(const float4*)(wq0 + kb);   // uniform -> s_load_dwordx4
      A1.v = *(const float4*)(wq1 + kb);
#pragma unroll
      for (int e = 0; e < 4; ++e) {
        const float4 g4 = *(const float4*)(Gn + (size_t)(kb + e) * 256 + lane * 4);
        const float a0 = A0.f[e], a1 = A1.f[e];
        tr0.x += a0 * g4.x; tr0.y += a0 * g4.y; tr0.z += a0 * g4.z; tr0.w += a0 * g4.w;
        tr1.x += a1 * g4.x; tr1.y += a1 * g4.y; tr1.z += a1 * g4.z; tr1.w += a1 * g4.w;
      }
    }
    tr0.x *= ivq0; tr0.y *= ivq0; tr0.z *= ivq0; tr0.w *= ivq0;
    tr1.x *= ivq1; tr1.y *= ivq1; tr1.z *= ivq1; tr1.w *= ivq1;
    *(float4*)(t_lds + (2 * w + 0) * TLD + lane * 4) = tr0;
    *(float4*)(t_lds + (2 * w + 1) * TLD + lane * 4) = tr1;
  }
  __syncthreads();

  // ------- P2: thread t = column d; L[i][t] = ivk*(T_i . Wk_row) + bias
  {
    float lreg[8];
#pragma unroll
    for (int i = 0; i < 8; ++i) lreg[i] = 0.f;
    const float ivk = kga[t] * rsqrtf(kva[t] + EPS);
    const float bkd = kbe[t] - kme[t] * ivk;
    float rkd = 0.f;
    const float* wkrow = Wk + (size_t)t * 256;
    for (int jb = 0; jb < 256; jb += 4) {
      const float4 w4 = *(const float4*)(wkrow + jb);
      const float4 r4 = *(const float4*)(r_lds + jb);     // uniform b128
      rkd += w4.x * r4.x + w4.y * r4.y + w4.z * r4.z + w4.w * r4.w;
#pragma unroll
      for (int i = 0; i < 8; ++i) {
        const float4 t4 = *(const float4*)(t_lds + i * TLD + jb);  // uniform b128
        lreg[i] += t4.x * w4.x + t4.y * w4.y + t4.z * w4.z + t4.w * w4.w;
      }
    }
#pragma unroll
    for (int i = 0; i < 8; ++i)
      p_lds[i * TLD + t] = ivk * lreg[i] + rq_lds[i] * bkd +
                           bq_lds[i] * (ivk * rkd) + 16384.0f * bq_lds[i] * bkd;
  }
  __syncthreads();

  // ------- P3: softmax; row i = t>>5, 32 lanes/row, 8 cols each (d = s + u*32)
  {
    const int i = t >> 5, s = t & 31;
    float* row = p_lds + i * TLD;
    float mx = -1e30f;
#pragma unroll
    for (int u = 0; u < 8; ++u) mx = fmaxf(mx, row[s + u * 32]);
    mx = fmaxf(mx, __shfl_xor(mx, 1));
    mx = fmaxf(mx, __shfl_xor(mx, 2));
    mx = fmaxf(mx, __shfl_xor(mx, 4));
    mx = fmaxf(mx, __shfl_xor(mx, 8));
    mx = fmaxf(mx, __shfl_xor(mx, 16));
    float sraw = 0.f, sbv = 0.f;
#pragma unroll
    for (int u = 0; u < 8; ++u) {
      const int d = s + u * 32;
      const float e = __expf(row[d] - mx);
      sraw += e;
      sbv += e * bv_lds[d];
      row[d] = e * ivv_lds[d];   // pre-scale by Dv for P4
    }
    sraw += __shfl_xor(sraw, 1);  sbv += __shfl_xor(sbv, 1);
    sraw += __shfl_xor(sraw, 2);  sbv += __shfl_xor(sbv, 2);
    sraw += __shfl_xor(sraw, 4);  sbv += __shfl_xor(sbv, 4);
    sraw += __shfl_xor(sraw, 8);  sbv += __shfl_xor(sbv, 8);
    sraw += __shfl_xor(sraw, 16); sbv += __shfl_xor(sbv, 16);
    if (s == 0) {
      rsum_lds[i] = sraw;
      cvec[n * 256 + r0 + i] = sbv / sraw;
    }
  }
  __syncthreads();

  // ------- P4: M[i][t] = (P_i . Wv_col_t) / rsum_i; Wv coalesced, P uniform b128
  {
    float mreg[8];
#pragma unroll
    for (int i = 0; i < 8; ++i) mreg[i] = 0.f;
    for (int db = 0; db < 256; db += 4) {
      float wv[4];
#pragma unroll
      for (int e = 0; e < 4; ++e) wv[e] = Wv[(size_t)(db + e) * 256 + t];
#pragma unroll
      for (int i = 0; i < 8; ++i) {
        const float4 p4 = *(const float4*)(p_lds + i * TLD + db);  // uniform b128
        mreg[i] += p4.x * wv[0] + p4.y * wv[1] + p4.z * wv[2] + p4.w * wv[3];
      }
    }
#pragma unroll
    for (int i = 0; i < 8; ++i)
      M[((size_t)n * 256 + r0 + i) * 256 + t] = f2bf(mreg[i] / rsum_lds[i]);
  }
}

// ----------------------------------------------------------------- kOut ----
// grid (256 s-chunks of 64, 8 batches), 256 threads (4 waves).
// out[:,s-chunk] = M @ x_bf16 + cvec + x (fp32 residual from LDS copy).
#define LDT 40   // padded LDS row stride for transposed x tile (bf16 elems)
__global__ __launch_bounds__(256, 2) void kOut(const float* __restrict__ x,
                                               const unsigned short* __restrict__ M,
                                               const float* __restrict__ cvec,
                                               float* __restrict__ out) {
  __shared__ __align__(16) unsigned short xt[64 * LDT];  // [s][ch] bf16
  __shared__ __align__(16) float xf[256 * 64];           // [ch][s] fp32 residual
  const int n = blockIdx.y, s0 = blockIdx.x * 64;
  const int tid = threadIdx.x;
  const float* xn = x + (size_t)n * 4194304;
  const unsigned short* Mn = M + (size_t)n * 65536;
  const int lane = tid & 63, w = tid >> 6;
  const int m = lane & 15, q = lane >> 4;

  f32x4 acc[4][4];
  const f32x4 z4 = {0.f, 0.f, 0.f, 0.f};
#pragma unroll
  for (int i = 0; i < 4; ++i)
#pragma unroll
    for (int ct = 0; ct < 4; ++ct) acc[i][ct] = z4;

  for (int kt = 0; kt < 8; ++kt) {
    __syncthreads();
#pragma unroll
    for (int u = 0; u < 2; ++u) {
      const int fidx = tid + u * 256;
      const int ch = fidx >> 4, f = fidx & 15;
      const float4 v = *(const float4*)(xn + (size_t)(kt * 32 + ch) * 16384 + s0 + f * 4);
      *(float4*)&xf[(kt * 32 + ch) * 64 + f * 4] = v;
      xt[(f * 4 + 0) * LDT + ch] = f2bf(v.x);
      xt[(f * 4 + 1) * LDT + ch] = f2bf(v.y);
      xt[(f * 4 + 2) * LDT + ch] = f2bf(v.z);
      xt[(f * 4 + 3) * LDT + ch] = f2bf(v.w);
    }
    __syncthreads();
    bf16x8 A[4], B[4];
#pragma unroll
    for (int i = 0; i < 4; ++i)
      A[i] = ld_frag(&Mn[((w * 4 + i) * 16 + m) * 256 + kt * 32 + q * 8]);
#pragma unroll
    for (int ct = 0; ct < 4; ++ct)
      B[ct] = ld_frag(&xt[(ct * 16 + m) * LDT + q * 8]);
#pragma unroll
    for (int i = 0; i < 4; ++i)
#pragma unroll
      for (int ct = 0; ct < 4; ++ct)
        acc[i][ct] = __builtin_amdgcn_mfma_f32_16x16x32_bf16(A[i], B[ct], acc[i][ct], 0, 0, 0);
  }
  // epilogue: c = w*64 + i*16 + q*4 + e ; s = ct*16 + m
#pragma unroll
  for (int i = 0; i < 4; ++i) {
    const int cb = w * 64 + i * 16 + q * 4;
#pragma unroll
    for (int e = 0; e < 4; ++e) {
      const int c = cb + e;
      const float cv = cvec[n * 256 + c];
      float* orow = out + ((size_t)n * 256 + c) * 16384 + s0;
#pragma unroll
      for (int ct = 0; ct < 4; ++ct) {
        const int s = ct * 16 + m;
        orow[s] = acc[i][ct][e] + cv + xf[c * 64 + s];
      }
    }
  }
}

// --------------------------------------------------------------- launch ----
extern "C" void kernel_launch(void* const* d_in, const int* in_sizes, int n_in,
                              void* d_out, int out_size, void* d_ws, size_t ws_size,
                              hipStream_t stream) {
  const float* x   = (const float*)d_in[0];
  const float* Wk  = (const float*)d_in[1];
  const float* kga = (const float*)d_in[2];
  const float* kbe = (const float*)d_in[3];
  const float* kme = (const float*)d_in[4];
  const float* kva = (const float*)d_in[5];
  const float* Wq  = (const float*)d_in[6];
  const float* qga = (const float*)d_in[7];
  const float* qbe = (const float*)d_in[8];
  const float* qme = (const float*)d_in[9];
  const float* qva = (const float*)d_in[10];
  const float* Wv  = (const float*)d_in[11];
  const float* vga = (const float*)d_in[12];
  const float* vbe = (const float*)d_in[13];
  const float* vme = (const float*)d_in[14];
  const float* vva = (const float*)d_in[15];

  // ws layout: G (2 MB) | M (1 MB) | cvec (8 KB) | rp (256 KB) | Gp (splits*2 MB)
  char* ws = (char*)d_ws;
  float* G           = (float*)(ws);
  unsigned short* Mm = (unsigned short*)(ws + 2097152);
  float* cv          = (float*)(ws + 3145728);
  float* rp          = (float*)(ws + 3153920);
  float* Gp          = (float*)(ws + 3416064);
  float* out         = (float*)d_out;

  int splits = 32;
  while (splits > 1 &&
         (size_t)3416064 + (size_t)splits * 8 * 65536 * 4 > ws_size)
    splits >>= 1;
  const int chunk = 16384 / splits;

  kGram<<<dim3(splits, 8), 512, 0, stream>>>(x, Gp, rp, chunk);
  kReduce<<<512, 256, 0, stream>>>(Gp, G, splits);
  kAttn<<<dim3(32, 8), 256, 0, stream>>>(G, rp, splits,
                                         Wq, qga, qbe, qme, qva,
                                         Wk, kga, kbe, kme, kva,
                                         Wv, vga, vbe, vme, vva,
                                         Mm, cv);
  kOut<<<dim3(256, 8), 256, 0, stream>>>(x, Mm, cv, out);
}